// Round 21
// baseline (67.646 us; speedup 1.0000x reference)
//
#include <hip/hip_runtime.h>
#include <math.h>

#define H 4096
#define W 4096
#define NC 512            // cells per dim (H/8)
#define NB 510            // blocks per dim (NC - 3 + 1)
#define ORI 9
#define NCELLS (NC * NC)  // 262144
#define NOUT (NB * NB * 81)  // 21068100

// ---- glibc flt-32 atanf/atan2f replication (fdlibm; pre-2.40 glibc) ----
__device__ __forceinline__ float fdlibm_atanf(float x) {
#pragma clang fp contract(off)
    const float one = 1.0f;
    const float aT0  = (float) 3.33333333333329318027e-01;
    const float aT1  = (float)-1.99999999998764832476e-01;
    const float aT2  = (float) 1.42857142725034663711e-01;
    const float aT3  = (float)-1.11111104054623557880e-01;
    const float aT4  = (float) 9.09088713343650656196e-02;
    const float aT5  = (float)-7.69187620504482999495e-02;
    const float aT6  = (float) 6.66107313738753120669e-02;
    const float aT7  = (float)-5.83357013379057348645e-02;
    const float aT8  = (float) 4.97687799461593236017e-02;
    const float aT9  = (float)-3.65315727442169155270e-02;
    const float aT10 = (float) 1.62858201153657823623e-02;
    const float athi[4] = {4.6364760399e-01f, 7.8539812565e-01f,
                           9.8279368877e-01f, 1.5707962513e+00f};
    const float atlo[4] = {5.0121582440e-09f, 3.7748947079e-08f,
                           3.4473217170e-08f, 7.5497894159e-08f};
    int hx = __float_as_int(x);
    int ix = hx & 0x7fffffff;
    int id;
    if (ix >= 0x4c800000) {
        if (ix > 0x7f800000) return x + x;
        float r = athi[3] + atlo[3];
        return (hx > 0) ? r : -r;
    }
    if (ix < 0x3ee00000) {
        if (ix < 0x31000000) return x;
        id = -1;
    } else {
        x = fabsf(x);
        if (ix < 0x3f980000) {
            if (ix < 0x3f300000) { id = 0; x = (2.0f * x - one) / (2.0f + x); }
            else                 { id = 1; x = (x - one) / (x + one); }
        } else {
            if (ix < 0x401c0000) { id = 2; x = (x - 1.5f) / (one + 1.5f * x); }
            else                 { id = 3; x = -1.0f / x; }
        }
    }
    float z = x * x;
    float w = z * z;
    float s1 = z * (aT0 + w * (aT2 + w * (aT4 + w * (aT6 + w * (aT8 + w * aT10)))));
    float s2 = w * (aT1 + w * (aT3 + w * (aT5 + w * (aT7 + w * aT9))));
    if (id < 0) return x - x * (s1 + s2);
    z = athi[id] - ((x * (s1 + s2) - atlo[id]) - x);
    return (hx < 0) ? -z : z;
}

__device__ __forceinline__ float fdlibm_atan2f(float y, float x) {
#pragma clang fp contract(off)
    const float tiny   = 1.0e-30f;
    const float pi     = 3.1415927410e+00f;
    const float pi_lo  = -8.7422776573e-08f;
    const float pi_o_2 = 1.5707963705e+00f;
    int hx = __float_as_int(x), ix = hx & 0x7fffffff;
    int hy = __float_as_int(y), iy = hy & 0x7fffffff;
    if (hx == 0x3f800000) return fdlibm_atanf(y);
    int m = ((hy >> 31) & 1) | ((hx >> 30) & 2);
    if (iy == 0) {
        switch (m) {
            case 0: case 1: return y;
            case 2: return pi + tiny;
            default: return -pi - tiny;
        }
    }
    if (ix == 0) return (hy < 0) ? -pi_o_2 - tiny : pi_o_2 + tiny;
    int k = (iy - ix) >> 23;
    float z;
    if (k > 26) { z = pi_o_2 + 0.5f * pi_lo; m &= 1; }
    else if (k < -26 && hx < 0) z = 0.0f;
    else z = fdlibm_atanf(fabsf(y / x));
    switch (m) {
        case 0: return z;
        case 1: return -z;
        case 2: return pi - (z - pi_lo);
        default: return (z - pi_lo) - pi;
    }
}

// EXACT bin for pixel (reload + IEEE pipeline). 0..8 or 9 (excluded).
__device__ __forceinline__ int slow_bin_px(const float* __restrict__ x,
                                           int grow, int gc,
                                           bool row_ok, bool col_ok) {
#pragma clang fp contract(off)
    float gy = 0.0f, gx = 0.0f;
    if (row_ok)
        gy = sqrtf(x[(grow + 1) * W + gc]) - sqrtf(x[(grow - 1) * W + gc]);
    if (col_ok)
        gx = sqrtf(x[grow * W + gc + 1]) - sqrtf(x[grow * W + gc - 1]);
    float ang = fdlibm_atan2f(gy, gx);
    const float RAD2DEG = (float)(180.0 / 3.14159265358979323846264338328);
    float deg = ang * RAD2DEG;
    float m = fmodf(deg, 180.0f);
    if (m < 0.0f) m += 180.0f;
    int bin = (int)(m / 20.0f);
    if (bin < 9 && m >= (float)((bin + 1) * 20)) bin++;
    else if (bin > 0 && m < (float)(bin * 20)) bin--;
    return bin;
}

#define T20 ((float) 0.36397023426620236135)
#define T40 ((float) 0.83909963117728001176)
#define T60 ((float) 1.73205080756887729353)
#define T80 ((float) 5.67128181961771110517)

// constant-index float4 component select (folds inside unrolled loops)
__device__ __forceinline__ float f4c(const float4& v, int c) {
    switch (c) { case 0: return v.x; case 1: return v.y;
                 case 2: return v.z; default: return v.w; }
}

// One 4-row pass: loads 6 float4 column-rows + 4 edge pairs, accumulates
// prefix-threshold sums. jb = 0 or 4 (compile-time); all indices constant.
__device__ __forceinline__ void hist_pass(const float* __restrict__ x, int crow,
                                          int gc0, int jb, int gcl, int gcr,
                                          bool okL, bool okR,
                                          float& SA, float& TA1, float& TA2,
                                          float& TA3, float& TA4,
                                          float& SB, float& TB1, float& TB2,
                                          float& TB3, float& TB4,
                                          unsigned& gbits) {
    int r0p = (crow << 3) + jb - 1;
    int rtop = (r0p < 0) ? 0 : r0p;                 // clamps feed only masked gy
    int rbot = (r0p + 5 > H - 1) ? (H - 1) : (r0p + 5);
    const float4* x4 = (const float4*)x;            // 1024 float4 per row
    int c4 = gc0 >> 2;

    float4 s4[6];
    s4[0] = x4[rtop * 1024 + c4];
#pragma unroll
    for (int k = 1; k < 5; ++k) s4[k] = x4[(r0p + k) * 1024 + c4];
    s4[5] = x4[rbot * 1024 + c4];
    float sL[4], sR[4];
#pragma unroll
    for (int jr = 0; jr < 4; ++jr) {
        int grow = (crow << 3) + jb + jr;
        sL[jr] = x[grow * W + gcl];
        sR[jr] = x[grow * W + gcr];
    }
#pragma unroll
    for (int k = 0; k < 6; ++k) {
        s4[k].x = __builtin_amdgcn_sqrtf(s4[k].x);
        s4[k].y = __builtin_amdgcn_sqrtf(s4[k].y);
        s4[k].z = __builtin_amdgcn_sqrtf(s4[k].z);
        s4[k].w = __builtin_amdgcn_sqrtf(s4[k].w);
    }
#pragma unroll
    for (int jr = 0; jr < 4; ++jr) {
        sL[jr] = __builtin_amdgcn_sqrtf(sL[jr]);
        sR[jr] = __builtin_amdgcn_sqrtf(sR[jr]);
    }

#pragma unroll
    for (int jr = 0; jr < 4; ++jr) {
        int grow = (crow << 3) + jb + jr;
        bool row_ok = (grow >= 1) && (grow <= H - 2);
#pragma unroll
        for (int c = 0; c < 4; ++c) {
            float gy = row_ok ? (f4c(s4[jr + 2], c) - f4c(s4[jr], c)) : 0.0f;
            float left  = (c == 0) ? sL[jr] : f4c(s4[jr + 1], c - 1);
            float right = (c == 3) ? sR[jr] : f4c(s4[jr + 1], c + 1);
            bool col_ok = (c == 0) ? okL : ((c == 3) ? okR : true);
            float gx = col_ok ? (right - left) : 0.0f;

            float a = fabsf(gy), b = fabsf(gx);
            float d1 = fmaf(b, -T20, a);
            float d2 = fmaf(b, -T40, a);
            float d3 = fmaf(b, -T60, a);
            float d4 = fmaf(b, -T80, a);
            float cm = fminf(fminf(fabsf(d1), fabsf(d2)),
                             fminf(fminf(fabsf(d3), fabsf(d4)), a));
            bool guard = cm < fmaf(1e-5f, a + b, 4e-6f);
            if (guard) gbits |= (1u << ((jb + jr) * 4 + c));

            bool opp = ((__float_as_int(gy) ^ __float_as_int(gx)) < 0);
            float mag = __builtin_amdgcn_sqrtf(fmaf(gy, gy, gx * gx));
            float magA = (!opp && !guard) ? mag : 0.0f;
            float magB = (opp && !guard) ? mag : 0.0f;

            SA  += magA;
            TA1 += (d1 > 0.0f) ? magA : 0.0f;
            TA2 += (d2 > 0.0f) ? magA : 0.0f;
            TA3 += (d3 > 0.0f) ? magA : 0.0f;
            TA4 += (d4 > 0.0f) ? magA : 0.0f;
            SB  += magB;
            TB1 += (d1 > 0.0f) ? magB : 0.0f;
            TB2 += (d2 > 0.0f) ? magB : 0.0f;
            TB3 += (d3 > 0.0f) ? magB : 0.0f;
            TB4 += (d4 > 0.0f) ? magB : 0.0f;
        }
    }
}

// Kernel A: lane = 4 columns; wave = 8 rows x 256 cols = 32 cells.
// TWO 4-row passes (6 float4 rows live instead of 10) to fit <=64 VGPR ->
// 8 waves/SIMD. Prefix-threshold accumulation persists across passes;
// DPP xor1 reduce (cell = 2 lanes); __ffs bit-exact cleanup at the end.
__global__ __launch_bounds__(256, 8) void hog_hist(const float* __restrict__ x,
                                                   float* __restrict__ hist,
                                                   float* __restrict__ q) {
    int t = threadIdx.x;
    int lane = t & 63;
    int wid = blockIdx.x * 4 + (t >> 6);
    int crow = wid >> 4;            // cell row 0..511
    int cs   = wid & 15;            // 256-col strip 0..15
    int gc0  = (cs << 8) + (lane << 2);   // first of this lane's 4 columns

    int gcl = (gc0 == 0) ? 0 : gc0 - 1;   // clamped edges feed only masked gx
    int gcr = (gc0 + 4 > W - 1) ? (W - 1) : gc0 + 4;
    bool okL = (gc0 >= 1);
    bool okR = (gc0 + 3 <= W - 2);

    float SA = 0.f, TA1 = 0.f, TA2 = 0.f, TA3 = 0.f, TA4 = 0.f;
    float SB = 0.f, TB1 = 0.f, TB2 = 0.f, TB3 = 0.f, TB4 = 0.f;
    unsigned gbits = 0;

    hist_pass(x, crow, gc0, 0, gcl, gcr, okL, okR,
              SA, TA1, TA2, TA3, TA4, SB, TB1, TB2, TB3, TB4, gbits);
    hist_pass(x, crow, gc0, 4, gcl, gcr, okL, okR,
              SA, TA1, TA2, TA3, TA4, SB, TB1, TB2, TB3, TB4, gbits);

    // reconstruct 9 bins from prefix sums (monotone d1>d2>d3>d4)
    float bb[9];
    bb[0] = SA - TA1;  bb[1] = TA1 - TA2;  bb[2] = TA2 - TA3;  bb[3] = TA3 - TA4;
    bb[4] = TA4 + TB4;
    bb[5] = TB3 - TB4; bb[6] = TB2 - TB3;  bb[7] = TB1 - TB2;  bb[8] = SB - TB1;

    // bit-exact cleanup: reload exact IEEE values from memory
    if (__any(gbits != 0)) {
        unsigned gb = gbits;
        while (gb) {
            int bpos = __ffs(gb) - 1;
            gb &= gb - 1;
            int j = bpos >> 2, c = bpos & 3;
            int grow = (crow << 3) + j;
            int gc = gc0 + c;
            bool row_ok = (grow >= 1) && (grow <= H - 2);
            bool col_ok = (gc >= 1) && (gc <= W - 2);
            int bin = slow_bin_px(x, grow, gc, row_ok, col_ok);
            float gyE = 0.0f, gxE = 0.0f;
            if (row_ok) gyE = sqrtf(x[(grow + 1) * W + gc]) - sqrtf(x[(grow - 1) * W + gc]);
            if (col_ok) gxE = sqrtf(x[grow * W + gc + 1]) - sqrtf(x[grow * W + gc - 1]);
            float mag = sqrtf(fmaf(gyE, gyE, gxE * gxE));
#pragma unroll
            for (int b2 = 0; b2 < 9; ++b2) bb[b2] += (bin == b2) ? mag : 0.0f;
        }
    }

    // reduce over the 2-lane cell group (one DPP xor1)
#pragma unroll
    for (int b2 = 0; b2 < 9; ++b2) {
        int tv = __builtin_amdgcn_update_dpp(0, __float_as_int(bb[b2]),
                                             0xB1, 0xF, 0xF, true);
        bb[b2] += __int_as_float(tv);
    }

    // writes: even lane -> bins 0..4 (+q), odd lane -> bins 5..8
    int cell = lane >> 1;                       // 0..31
    int k = lane & 1;
    int cbase = crow * (NC * ORI) + ((cs << 5) + cell) * 9;
#pragma unroll
    for (int e = 0; e < 5; ++e) {
        float v0 = bb[e];
        float v1 = (e < 4) ? bb[5 + e] : 0.0f;  // const indices
        float val = k ? v1 : v0;
        int off = k ? (5 + e) : e;
        if (!k || e < 4) hist[cbase + off] = val * (1.0f / 64.0f);
    }
    if (k == 0) {
        float qq = 0.0f;
#pragma unroll
        for (int b2 = 0; b2 < 9; ++b2) {
            float h = bb[b2] * (1.0f / 64.0f);
            qq = fmaf(h, h, qq);
        }
        q[crow * NC + (cs << 5) + cell] = qq;
    }
}

// Kernel B: inv(i,j) = rsqrt(3x3 box-sum of q + EPS^2)
__global__ __launch_bounds__(256) void hog_inv(const float* __restrict__ q,
                                               float* __restrict__ inv) {
    int t = blockIdx.x * 256 + threadIdx.x;
    if (t >= NB * NB) return;
    int i = t / NB;
    int j = t - i * NB;
    float ssq = 0.0f;
#pragma unroll
    for (int bi = 0; bi < 3; ++bi)
#pragma unroll
        for (int bj = 0; bj < 3; ++bj)
            ssq += q[(i + bi) * NC + (j + bj)];
    inv[t] = 1.0f / sqrtf(ssq + 1e-10f);
}

// Kernel C: float4 per thread — 1/4 threads, 16B coalesced stores.
__global__ __launch_bounds__(256) void hog_norm4(const float* __restrict__ hist,
                                                 const float* __restrict__ inv,
                                                 float4* __restrict__ out4, int n4) {
    int v = blockIdx.x * 256 + threadIdx.x;
    if (v >= n4) return;
    int k0 = v * 4;
    float r[4];
#pragma unroll
    for (int e = 0; e < 4; ++e) {
        int k = k0 + e;
        int pidx = k / 81;
        int e81 = k - pidx * 81;
        int i = pidx / NB;
        int j = pidx - i * NB;
        int bi = e81 / 27;
        int rr = e81 - bi * 27;
        int bj = rr / 9;
        int o = rr - bj * 9;
        r[e] = hist[((i + bi) * NC + (j + bj)) * ORI + o] * inv[pidx];
    }
    out4[v] = make_float4(r[0], r[1], r[2], r[3]);
}

extern "C" void kernel_launch(void* const* d_in, const int* in_sizes, int n_in,
                              void* d_out, int out_size, void* d_ws, size_t ws_size,
                              hipStream_t stream) {
    const float* x = (const float*)d_in[0];
    float* out = (float*)d_out;
    float* hist = (float*)d_ws;                     // 9.44 MB
    float* inv  = hist + NCELLS * ORI;              // 1.04 MB
    float* q = out + (NOUT - NCELLS);               // d_out tail (overwritten by C)

    hog_hist<<<(NC * 16) / 4, 256, 0, stream>>>(x, hist, q);   // 2048 blocks
    hog_inv<<<(NB * NB + 255) / 256, 256, 0, stream>>>(q, inv);
    int n4 = out_size / 4;                                      // 21068100 = 4*5267025
    hog_norm4<<<(n4 + 255) / 256, 256, 0, stream>>>(hist, inv, (float4*)out, n4);
}

// Round 22
// 65.682 us; speedup vs baseline: 1.0299x; 1.0299x over previous
//
#include <hip/hip_runtime.h>
#include <math.h>

#define H 4096
#define W 4096
#define NC 512            // cells per dim (H/8)
#define NB 510            // blocks per dim (NC - 3 + 1)
#define ORI 9
#define NCELLS (NC * NC)  // 262144
#define NOUT (NB * NB * 81)  // 21068100

// ---- glibc flt-32 atanf/atan2f replication (fdlibm; pre-2.40 glibc) ----
// The np reference binning matches glibc's ~2-ulp atan2f, not a correctly-
// rounded one (r1-r3 evidence); this replica is bit-exact on the slow path.
__device__ __forceinline__ float fdlibm_atanf(float x) {
#pragma clang fp contract(off)
    const float one = 1.0f;
    const float aT0  = (float) 3.33333333333329318027e-01;
    const float aT1  = (float)-1.99999999998764832476e-01;
    const float aT2  = (float) 1.42857142725034663711e-01;
    const float aT3  = (float)-1.11111104054623557880e-01;
    const float aT4  = (float) 9.09088713343650656196e-02;
    const float aT5  = (float)-7.69187620504482999495e-02;
    const float aT6  = (float) 6.66107313738753120669e-02;
    const float aT7  = (float)-5.83357013379057348645e-02;
    const float aT8  = (float) 4.97687799461593236017e-02;
    const float aT9  = (float)-3.65315727442169155270e-02;
    const float aT10 = (float) 1.62858201153657823623e-02;
    const float athi[4] = {4.6364760399e-01f, 7.8539812565e-01f,
                           9.8279368877e-01f, 1.5707962513e+00f};
    const float atlo[4] = {5.0121582440e-09f, 3.7748947079e-08f,
                           3.4473217170e-08f, 7.5497894159e-08f};
    int hx = __float_as_int(x);
    int ix = hx & 0x7fffffff;
    int id;
    if (ix >= 0x4c800000) {
        if (ix > 0x7f800000) return x + x;
        float r = athi[3] + atlo[3];
        return (hx > 0) ? r : -r;
    }
    if (ix < 0x3ee00000) {
        if (ix < 0x31000000) return x;
        id = -1;
    } else {
        x = fabsf(x);
        if (ix < 0x3f980000) {
            if (ix < 0x3f300000) { id = 0; x = (2.0f * x - one) / (2.0f + x); }
            else                 { id = 1; x = (x - one) / (x + one); }
        } else {
            if (ix < 0x401c0000) { id = 2; x = (x - 1.5f) / (one + 1.5f * x); }
            else                 { id = 3; x = -1.0f / x; }
        }
    }
    float z = x * x;
    float w = z * z;
    float s1 = z * (aT0 + w * (aT2 + w * (aT4 + w * (aT6 + w * (aT8 + w * aT10)))));
    float s2 = w * (aT1 + w * (aT3 + w * (aT5 + w * (aT7 + w * aT9))));
    if (id < 0) return x - x * (s1 + s2);
    z = athi[id] - ((x * (s1 + s2) - atlo[id]) - x);
    return (hx < 0) ? -z : z;
}

__device__ __forceinline__ float fdlibm_atan2f(float y, float x) {
#pragma clang fp contract(off)
    const float tiny   = 1.0e-30f;
    const float pi     = 3.1415927410e+00f;
    const float pi_lo  = -8.7422776573e-08f;
    const float pi_o_2 = 1.5707963705e+00f;
    int hx = __float_as_int(x), ix = hx & 0x7fffffff;
    int hy = __float_as_int(y), iy = hy & 0x7fffffff;
    if (hx == 0x3f800000) return fdlibm_atanf(y);
    int m = ((hy >> 31) & 1) | ((hx >> 30) & 2);
    if (iy == 0) {
        switch (m) {
            case 0: case 1: return y;
            case 2: return pi + tiny;
            default: return -pi - tiny;
        }
    }
    if (ix == 0) return (hy < 0) ? -pi_o_2 - tiny : pi_o_2 + tiny;
    int k = (iy - ix) >> 23;
    float z;
    if (k > 26) { z = pi_o_2 + 0.5f * pi_lo; m &= 1; }
    else if (k < -26 && hx < 0) z = 0.0f;
    else z = fdlibm_atanf(fabsf(y / x));
    switch (m) {
        case 0: return z;
        case 1: return -z;
        case 2: return pi - (z - pi_lo);
        default: return (z - pi_lo) - pi;
    }
}

// EXACT bin for pixel (reload + IEEE pipeline). 0..8 or 9 (excluded).
__device__ __forceinline__ int slow_bin_px(const float* __restrict__ x,
                                           int grow, int gc,
                                           bool row_ok, bool col_ok) {
#pragma clang fp contract(off)
    float gy = 0.0f, gx = 0.0f;
    if (row_ok)
        gy = sqrtf(x[(grow + 1) * W + gc]) - sqrtf(x[(grow - 1) * W + gc]);
    if (col_ok)
        gx = sqrtf(x[grow * W + gc + 1]) - sqrtf(x[grow * W + gc - 1]);
    float ang = fdlibm_atan2f(gy, gx);
    const float RAD2DEG = (float)(180.0 / 3.14159265358979323846264338328);
    float deg = ang * RAD2DEG;
    float m = fmodf(deg, 180.0f);
    if (m < 0.0f) m += 180.0f;
    int bin = (int)(m / 20.0f);
    if (bin < 9 && m >= (float)((bin + 1) * 20)) bin++;
    else if (bin > 0 && m < (float)(bin * 20)) bin--;
    return bin;
}

#define T20 ((float) 0.36397023426620236135)
#define T40 ((float) 0.83909963117728001176)
#define T60 ((float) 1.73205080756887729353)
#define T80 ((float) 5.67128181961771110517)

// constant-index float4 component select (folds inside unrolled loops)
__device__ __forceinline__ float f4c(const float4& v, int c) {
    switch (c) { case 0: return v.x; case 1: return v.y;
                 case 2: return v.z; default: return v.w; }
}

// Kernel A (round-20 best): lane = 4 columns (float4). Wave = 8 rows x 256
// cols = 32 cells. Zero LDS / zero atomics (the r16 bisection showed LDS
// ds_add_f32 same-address RMW serialization was the historical ~100us floor).
// Hoisted loads; prefix-threshold accumulation (monotone d1>d2>d3>d4 ->
// bins by subtraction); ONE DPP xor1 reduce (cell = 2 lanes); __ffs-driven
// bit-exact fdlibm cleanup (~rare) reloading exact IEEE values from memory.
__global__ __launch_bounds__(256, 4) void hog_hist(const float* __restrict__ x,
                                                   float* __restrict__ hist,
                                                   float* __restrict__ q) {
    int t = threadIdx.x;
    int w = t >> 6, lane = t & 63;
    int wid = blockIdx.x * 4 + w;
    int crow = wid >> 4;            // cell row 0..511
    int cs   = wid & 15;            // 256-col strip 0..15
    int gc0  = (cs << 8) + (lane << 2);   // first of this lane's 4 columns

    int r0 = (crow << 3) - 1;
    int rtop = (r0 < 0) ? 0 : r0;               // clamped rows feed only masked gy
    int rbot = (r0 + 9 > H - 1) ? (H - 1) : (r0 + 9);
    int gcl = (gc0 == 0) ? 0 : gc0 - 1;         // clamped edges feed only masked gx
    int gcr = (gc0 + 4 > W - 1) ? (W - 1) : gc0 + 4;

    // ---- hoisted loads: 10 float4 column stack + 16 scalar edges ----
    const float4* x4 = (const float4*)x;        // 1024 float4 per row
    int c4 = (gc0 >> 2);
    float4 s4[10];
    s4[0] = x4[rtop * 1024 + c4];
#pragma unroll
    for (int k = 1; k < 9; ++k) s4[k] = x4[(r0 + k) * 1024 + c4];
    s4[9] = x4[rbot * 1024 + c4];
    float sL[8], sR[8];
#pragma unroll
    for (int j = 0; j < 8; ++j) {
        int grow = (crow << 3) + j;
        sL[j] = x[grow * W + gcl];
        sR[j] = x[grow * W + gcr];
    }
    // ---- fast sqrt everything (value-level; masking at gy/gx) ----
#pragma unroll
    for (int k = 0; k < 10; ++k) {
        s4[k].x = __builtin_amdgcn_sqrtf(s4[k].x);
        s4[k].y = __builtin_amdgcn_sqrtf(s4[k].y);
        s4[k].z = __builtin_amdgcn_sqrtf(s4[k].z);
        s4[k].w = __builtin_amdgcn_sqrtf(s4[k].w);
    }
#pragma unroll
    for (int j = 0; j < 8; ++j) {
        sL[j] = __builtin_amdgcn_sqrtf(sL[j]);
        sR[j] = __builtin_amdgcn_sqrtf(sR[j]);
    }

    bool okL = (gc0 >= 1);                 // c==0 col_ok (false only cs0/lane0)
    bool okR = (gc0 + 3 <= W - 2);         // c==3 col_ok (false only cs15/lane63)
    float SA = 0.f, TA1 = 0.f, TA2 = 0.f, TA3 = 0.f, TA4 = 0.f;
    float SB = 0.f, TB1 = 0.f, TB2 = 0.f, TB3 = 0.f, TB4 = 0.f;
    unsigned gbits = 0;                    // 32 pixels -> 32 guard bits

#pragma unroll
    for (int j = 0; j < 8; ++j) {
        int grow = (crow << 3) + j;
        bool row_ok = (grow >= 1) && (grow <= H - 2);
#pragma unroll
        for (int c = 0; c < 4; ++c) {
            float gy = row_ok ? (f4c(s4[j + 2], c) - f4c(s4[j], c)) : 0.0f;
            float left  = (c == 0) ? sL[j] : f4c(s4[j + 1], c - 1);
            float right = (c == 3) ? sR[j] : f4c(s4[j + 1], c + 1);
            bool col_ok = (c == 0) ? okL : ((c == 3) ? okR : true);
            float gx = col_ok ? (right - left) : 0.0f;

            float a = fabsf(gy), b = fabsf(gx);
            float d1 = fmaf(b, -T20, a);
            float d2 = fmaf(b, -T40, a);
            float d3 = fmaf(b, -T60, a);
            float d4 = fmaf(b, -T80, a);
            float cm = fminf(fminf(fabsf(d1), fabsf(d2)),
                             fminf(fminf(fabsf(d3), fabsf(d4)), a));
            bool guard = cm < fmaf(1e-5f, a + b, 4e-6f);
            if (guard) gbits |= (1u << (j * 4 + c));

            bool opp = ((__float_as_int(gy) ^ __float_as_int(gx)) < 0);
            float mag = __builtin_amdgcn_sqrtf(fmaf(gy, gy, gx * gx));
            float magA = (!opp && !guard) ? mag : 0.0f;
            float magB = (opp && !guard) ? mag : 0.0f;

            SA  += magA;
            TA1 += (d1 > 0.0f) ? magA : 0.0f;
            TA2 += (d2 > 0.0f) ? magA : 0.0f;
            TA3 += (d3 > 0.0f) ? magA : 0.0f;
            TA4 += (d4 > 0.0f) ? magA : 0.0f;
            SB  += magB;
            TB1 += (d1 > 0.0f) ? magB : 0.0f;
            TB2 += (d2 > 0.0f) ? magB : 0.0f;
            TB3 += (d3 > 0.0f) ? magB : 0.0f;
            TB4 += (d4 > 0.0f) ? magB : 0.0f;
        }
    }

    // reconstruct 9 bins from prefix sums (monotone d1>d2>d3>d4)
    float bb[9];
    bb[0] = SA - TA1;  bb[1] = TA1 - TA2;  bb[2] = TA2 - TA3;  bb[3] = TA3 - TA4;
    bb[4] = TA4 + TB4;
    bb[5] = TB3 - TB4; bb[6] = TB2 - TB3;  bb[7] = TB1 - TB2;  bb[8] = SB - TB1;

    // bit-exact cleanup: reload exact IEEE values from memory (compact loop,
    // no dynamic register indexing; exact mag here is value-level ~ulp)
    if (__any(gbits != 0)) {
        unsigned gb = gbits;
        while (gb) {
            int bpos = __ffs(gb) - 1;
            gb &= gb - 1;
            int j = bpos >> 2, c = bpos & 3;
            int grow = (crow << 3) + j;
            int gc = gc0 + c;
            bool row_ok = (grow >= 1) && (grow <= H - 2);
            bool col_ok = (gc >= 1) && (gc <= W - 2);
            int bin = slow_bin_px(x, grow, gc, row_ok, col_ok);
            float gyE = 0.0f, gxE = 0.0f;
            if (row_ok) gyE = sqrtf(x[(grow + 1) * W + gc]) - sqrtf(x[(grow - 1) * W + gc]);
            if (col_ok) gxE = sqrtf(x[grow * W + gc + 1]) - sqrtf(x[grow * W + gc - 1]);
            float mag = sqrtf(fmaf(gyE, gyE, gxE * gxE));
#pragma unroll
            for (int b2 = 0; b2 < 9; ++b2) bb[b2] += (bin == b2) ? mag : 0.0f;
        }
    }

    // reduce over the 2-lane cell group (one DPP xor1)
#pragma unroll
    for (int b2 = 0; b2 < 9; ++b2) {
        int tv = __builtin_amdgcn_update_dpp(0, __float_as_int(bb[b2]),
                                             0xB1, 0xF, 0xF, true);
        bb[b2] += __int_as_float(tv);
    }

    // writes: even lane -> bins 0..4 (+q), odd lane -> bins 5..8
    int cell = lane >> 1;                       // 0..31
    int k = lane & 1;
    int cbase = crow * (NC * ORI) + ((cs << 5) + cell) * 9;
#pragma unroll
    for (int e = 0; e < 5; ++e) {
        float v0 = bb[e];
        float v1 = (e < 4) ? bb[5 + e] : 0.0f;  // const indices
        float val = k ? v1 : v0;
        int off = k ? (5 + e) : e;
        if (!k || e < 4) hist[cbase + off] = val * (1.0f / 64.0f);
    }
    if (k == 0) {
        float qq = 0.0f;
#pragma unroll
        for (int b2 = 0; b2 < 9; ++b2) {
            float h = bb[b2] * (1.0f / 64.0f);
            qq = fmaf(h, h, qq);
        }
        q[crow * NC + (cs << 5) + cell] = qq;
    }
}

// Kernel B: inv(i,j) = rsqrt(3x3 box-sum of q + EPS^2)
__global__ __launch_bounds__(256) void hog_inv(const float* __restrict__ q,
                                               float* __restrict__ inv) {
    int t = blockIdx.x * 256 + threadIdx.x;
    if (t >= NB * NB) return;
    int i = t / NB;
    int j = t - i * NB;
    float ssq = 0.0f;
#pragma unroll
    for (int bi = 0; bi < 3; ++bi)
#pragma unroll
        for (int bj = 0; bj < 3; ++bj)
            ssq += q[(i + bi) * NC + (j + bj)];
    inv[t] = 1.0f / sqrtf(ssq + 1e-10f);
}

// Kernel C: float4 per thread — 1/4 threads, 16B coalesced stores.
__global__ __launch_bounds__(256) void hog_norm4(const float* __restrict__ hist,
                                                 const float* __restrict__ inv,
                                                 float4* __restrict__ out4, int n4) {
    int v = blockIdx.x * 256 + threadIdx.x;
    if (v >= n4) return;
    int k0 = v * 4;
    float r[4];
#pragma unroll
    for (int e = 0; e < 4; ++e) {
        int k = k0 + e;
        int pidx = k / 81;
        int e81 = k - pidx * 81;
        int i = pidx / NB;
        int j = pidx - i * NB;
        int bi = e81 / 27;
        int rr = e81 - bi * 27;
        int bj = rr / 9;
        int o = rr - bj * 9;
        r[e] = hist[((i + bi) * NC + (j + bj)) * ORI + o] * inv[pidx];
    }
    out4[v] = make_float4(r[0], r[1], r[2], r[3]);
}

extern "C" void kernel_launch(void* const* d_in, const int* in_sizes, int n_in,
                              void* d_out, int out_size, void* d_ws, size_t ws_size,
                              hipStream_t stream) {
    const float* x = (const float*)d_in[0];
    float* out = (float*)d_out;
    float* hist = (float*)d_ws;                     // 9.44 MB
    float* inv  = hist + NCELLS * ORI;              // 1.04 MB
    float* q = out + (NOUT - NCELLS);               // d_out tail (overwritten by C)

    hog_hist<<<(NC * 16) / 4, 256, 0, stream>>>(x, hist, q);   // 2048 blocks
    hog_inv<<<(NB * NB + 255) / 256, 256, 0, stream>>>(q, inv);
    int n4 = out_size / 4;                                      // 21068100 = 4*5267025
    hog_norm4<<<(n4 + 255) / 256, 256, 0, stream>>>(hist, inv, (float4*)out, n4);
}